// Round 7
// baseline (10513.180 us; speedup 1.0000x reference)
//
#include <hip/hip_runtime.h>
#include <math.h>

#define HID    512
#define NIN    256
#define TIN    4096
#define NSTEP  1023
#define NEVAL  (NSTEP*4)
#define NWG    16
#define SLICE  32
#define NTH    1024
#define NLAUNCH 128
#define XPAD   16          // FAST-mode stride: 1 word per 128B line (L2 RMW de-serialization)

// ---------- agent-scope helpers (LLC point; PROVEN channel, rounds 2-6) ----------
__device__ __forceinline__ unsigned ag_load(const unsigned* p) {
  return __hip_atomic_load(p, __ATOMIC_RELAXED, __HIP_MEMORY_SCOPE_AGENT);
}
__device__ __forceinline__ void ag_store(unsigned* p, unsigned v) {
  __hip_atomic_store(p, v, __ATOMIC_RELAXED, __HIP_MEMORY_SCOPE_AGENT);
}
__device__ __forceinline__ unsigned ag_add(unsigned* p, unsigned v) {
  return __hip_atomic_fetch_add(p, v, __ATOMIC_RELAXED, __HIP_MEMORY_SCOPE_AGENT);
}
__device__ __forceinline__ void ag_cas(unsigned* p, unsigned c, unsigned v) {
  unsigned e = c;
  __hip_atomic_compare_exchange_strong(p, &e, v, __ATOMIC_RELAXED, __ATOMIC_RELAXED,
                                       __HIP_MEMORY_SCOPE_AGENT);
}

// ---------- L2-point (non-sc1) atomics: executed at the XCD's L2, never stale-L1 ----------
__device__ __forceinline__ unsigned long long l2_poll64(unsigned long long* p) {
  unsigned long long old, zero = 0;
  asm volatile("global_atomic_add_x2 %0, %1, %2, off sc0\n\ts_waitcnt vmcnt(0)"
               : "=v"(old) : "v"(p), "v"(zero) : "memory");
  return old;
}
__device__ __forceinline__ void l2_put64(unsigned long long* p, unsigned long long v) {
  asm volatile("global_atomic_swap_x2 %0, %1, off" :: "v"(p), "v"(v) : "memory");
}
__device__ __forceinline__ unsigned l2_poll32(unsigned* p) {
  unsigned old, zero = 0;
  asm volatile("global_atomic_add %0, %1, %2, off sc0\n\ts_waitcnt vmcnt(0)"
               : "=v"(old) : "v"(p), "v"(zero) : "memory");
  return old;
}
__device__ __forceinline__ void l2_put32(unsigned* p, unsigned v) {
  asm volatile("global_atomic_swap %0, %1, off" :: "v"(p), "v"(v) : "memory");
}

// searchsorted(linspace(0,1,4096), t, side='left') clipped to [0, 4095]
__device__ __forceinline__ int zoh_index(float t) {
  const float delta = 1.0f / 4095.0f;
  int lo = 0, hi = TIN;
  while (lo < hi) {
    int mid = (lo + hi) >> 1;
    float g = (float)mid * delta;
    if (g < t) lo = mid + 1; else hi = mid;
  }
  return lo > TIN - 1 ? TIN - 1 : lo;
}

// Round-3-proven gu precompute: gu[e][0:512]=U_tau@I+b_tau, gu[e][512:1024]=U_f@I+b_f
__global__ void __launch_bounds__(256)
gu_kernel(const float* __restrict__ I_seq, const float* __restrict__ t_save,
          const float* __restrict__ U_tau, const float* __restrict__ b_tau,
          const float* __restrict__ U_f,   const float* __restrict__ b_f,
          float* __restrict__ gu)
{
  __shared__ float Ish[NIN];
  const int e = blockIdx.x;
  const int tid = threadIdx.x;
  const int n = e >> 2, s = e & 3;
  const float t0 = t_save[n], t1 = t_save[n + 1];
  const float dt = t1 - t0;
  const float third = 1.0f / 3.0f;
  float t;
  if      (s == 0) t = t0;
  else if (s == 1) t = t0 + dt * third;
  else if (s == 2) t = t0 + (dt * 2.0f) * third;
  else             t = t1;
  const int idx = zoh_index(t);
  Ish[tid] = I_seq[idx * NIN + tid];
  __syncthreads();
  float* go = gu + (size_t)e * 1024;
  #pragma unroll
  for (int m = 0; m < 2; ++m) {
    const float* __restrict__ U = m ? U_f : U_tau;
    const float* __restrict__ b = m ? b_f : b_tau;
    #pragma unroll
    for (int hh = 0; hh < 2; ++hh) {
      const int h = tid + hh * 256;
      const float4* __restrict__ Ur = (const float4*)(U + (size_t)h * NIN);
      float acc = 0.f;
      #pragma unroll 8
      for (int k = 0; k < NIN / 4; ++k) {
        float4 u = Ur[k];
        acc = fmaf(u.x, Ish[4*k+0], acc);
        acc = fmaf(u.y, Ish[4*k+1], acc);
        acc = fmaf(u.z, Ish[4*k+2], acc);
        acc = fmaf(u.w, Ish[4*k+3], acc);
      }
      go[m * 512 + h] = acc + b[h];
    }
  }
}

// The proven round-3 scan body, parameterized on slot stride + exchange mechanism.
template<int STRIDE, bool FAST>
__device__ __forceinline__ void scan_loop(int rank, int tid,
    const float* __restrict__ x0, const float* __restrict__ t_save,
    const float* __restrict__ W_tau, const float* __restrict__ tau0,
    const float* __restrict__ W_f,  const float* __restrict__ gu,
    unsigned long long* xslot, float* __restrict__ out,
    float* xsp, float* pre)
{
  const int row  = tid >> 4;    // 0..63
  const int seg  = tid & 15;    // 0..15, 32 columns each
  const int base = rank * SLICE;

  const float* wrow = ((row < SLICE)
      ? (W_tau + (size_t)(base + row) * HID)
      : (W_f   + (size_t)(base + row - SLICE) * HID)) + seg * 32;

  float4 w4[8];
  #pragma unroll
  for (int t = 0; t < 8; ++t) w4[t] = ((const float4*)wrow)[t];

  float y0 = 0.f, k1 = 0.f, k2 = 0.f, k3 = 0.f, curx = 0.f, tz = 0.f;
  if (tid < SLICE) {
    y0   = x0[base + tid];
    curx = y0;
    tz   = tau0[base + tid];
    out[base + tid] = y0;              // out[0] = x0
  }

  for (int n = 0; n < NSTEP; ++n) {
    const float t0 = t_save[n], t1 = t_save[n + 1];
    const float dt = t1 - t0;
    #pragma unroll
    for (int s = 0; s < 4; ++s) {
      const int e = (n << 2) + s;

      // gu loads issued first: latency hides under the poll below
      float gt = 0.f, gf = 0.f;
      if (tid < SLICE) {
        const float* g = gu + (size_t)e * 1024 + base + tid;
        gt = g[0];
        gf = g[512];
      }

      // ---- acquire x_e: spin on packed (tag,value) words, fill LDS ----
      if (tid < HID) {
        float v;
        if (e == 0) {
          v = x0[tid];
        } else {
          unsigned long long* src = xslot + ((size_t)(e & 1) * HID + tid) * STRIDE;
          unsigned long long pk;
          if (FAST) {
            do { pk = l2_poll64(src); } while ((unsigned)(pk >> 32) != (unsigned)e);
          } else {
            do {
              pk = __hip_atomic_load(src, __ATOMIC_RELAXED, __HIP_MEMORY_SCOPE_AGENT);
            } while ((unsigned)(pk >> 32) != (unsigned)e);
          }
          v = __uint_as_float((unsigned)pk);
        }
        xsp[(tid >> 5) * 36 + (tid & 31)] = v;
      }
      __syncthreads();

      // ---- matvec: 32 MACs/thread from VGPR weights + LDS x ----
      float acc = 0.f;
      #pragma unroll
      for (int t = 0; t < 8; ++t) {
        const float4 xv = *reinterpret_cast<const float4*>(&xsp[seg * 36 + 4 * t]);
        acc = fmaf(w4[t].x, xv.x, acc);
        acc = fmaf(w4[t].y, xv.y, acc);
        acc = fmaf(w4[t].z, xv.z, acc);
        acc = fmaf(w4[t].w, xv.w, acc);
      }
      acc += __shfl_xor(acc, 1);
      acc += __shfl_xor(acc, 2);
      acc += __shfl_xor(acc, 4);
      acc += __shfl_xor(acc, 8);
      if ((tid & 15) == 0) pre[row] = acc;
      __syncthreads();

      // ---- elementwise + RK4 update; packed store IS the release ----
      if (tid < SLICE) {
        const float zt  = pre[tid] + gt;
        const float zf  = pre[SLICE + tid] + gf;
        const float ez  = __expf(-fabsf(zt));
        const float sp  = fmaxf(zt, 0.f) + __logf(1.f + ez);
        const float tau = tz + sp;
        const float ef  = __expf(-2.f * fabsf(zf));
        const float th  = (1.f - ef) / (1.f + ef);
        const float f   = (zf >= 0.f) ? th : -th;
        const float d   = f - curx / tau;
        float xnew;
        if      (s == 0) { k1 = d; xnew = y0 + dt * k1 * (1.0f/3.0f); }
        else if (s == 1) { k2 = d; xnew = y0 + dt * (k2 - k1 * (1.0f/3.0f)); }
        else if (s == 2) { k3 = d; xnew = y0 + dt * (k1 - k2 + k3); }
        else             { xnew = y0 + (k1 + 3.0f * (k2 + k3) + d) * dt * 0.125f; y0 = xnew; }
        curx = xnew;
        const unsigned long long pk =
            ((unsigned long long)(unsigned)(e + 1) << 32) |
            (unsigned long long)__float_as_uint(xnew);
        unsigned long long* dst =
            xslot + ((size_t)((e + 1) & 1) * HID + base + tid) * STRIDE;
        if (FAST) l2_put64(dst, pk);
        else __hip_atomic_store(dst, pk, __ATOMIC_RELAXED, __HIP_MEMORY_SCOPE_AGENT);
        if (s == 3) out[(size_t)(n + 1) * HID + base + tid] = xnew;
      }
      // no trailing barrier: the two barriers above order LDS reuse (round-3 proven)
    }
  }
}

// ctl[0..7]=per-XCD tickets [8]=winner(0/xcd+1/9) [9]=ack [10]=okc [11]=mode
// [12]=global ticket [13]=generation marker. pword = probe word (own line).
__global__ void __launch_bounds__(NTH, 1)
ltc_main(const float* __restrict__ x0, const float* __restrict__ t_save,
         const float* __restrict__ W_tau, const float* __restrict__ tau0,
         const float* __restrict__ W_f,  const float* __restrict__ gu,
         unsigned long long* xslot, unsigned* ctl, unsigned* pword,
         float* __restrict__ out)
{
  __shared__ float xsp[16 * 36];
  __shared__ float pre[64];
  __shared__ int sh_rank, sh_mode;
  const int tid = threadIdx.x;

  if (tid == 0) {
    // ---- XCD election (bounded; fallback = first-16-by-global-ticket) ----
    const int xcd = __builtin_amdgcn_s_getreg(6164) & 7;   // hwreg(HW_REG_XCC_ID,0,4)
    const int tk  = (int)ag_add(&ctl[xcd], 1u);
    const int gtk = (int)ag_add(&ctl[12], 1u);
    if (tk == NWG - 1) ag_cas(&ctl[8], 0u, (unsigned)(xcd + 1));
    unsigned w = 0;
    for (int it = 0; it < (1 << 20) && !(w = ag_load(&ctl[8])); ++it)
      __builtin_amdgcn_s_sleep(1);
    if (!w) { ag_cas(&ctl[8], 0u, 9u); w = ag_load(&ctl[8]); }
    int rank = -1;
    if (w == 9u) { if (gtk < NWG) rank = gtk; }
    else if ((int)(w - 1) == xcd && tk < NWG) rank = tk;

    int mode = 0;
    if (rank >= 0) {
      // ---- warm-line 3-generation L2-coherence probe (all spins bounded) ----
      int myok = 1;
      for (unsigned g = 1; g <= 3; ++g) {
        if (rank == 0) { l2_put32(pword, g); ag_store(&ctl[13], g); }
        else {
          unsigned m = 0;
          for (int it = 0; it < (1 << 20) && (m = ag_load(&ctl[13])) < g; ++it)
            __builtin_amdgcn_s_sleep(1);
          int ok = 0;
          if (m >= g)
            for (int it = 0; it < (1 << 16); ++it)
              if (l2_poll32(pword) == g) { ok = 1; break; }
          myok &= ok;
        }
        ag_add(&ctl[9], 1u);
        if (rank == 0)
          while (ag_load(&ctl[9]) < 16u * g) __builtin_amdgcn_s_sleep(1);
      }
      ag_add(&ctl[10], (unsigned)myok);
      ag_add(&ctl[9], 1u);
      if (rank == 0) {
        while (ag_load(&ctl[9]) < 64u) __builtin_amdgcn_s_sleep(1);
        ag_store(&ctl[11], ag_load(&ctl[10]) == (unsigned)NWG ? 2u : 1u);
      }
      unsigned md;
      while (!(md = ag_load(&ctl[11]))) __builtin_amdgcn_s_sleep(1);
      mode = (int)md;
    }
    sh_rank = rank;
    sh_mode = mode;
  }
  __syncthreads();
  const int rank = sh_rank;
  if (rank < 0) return;                       // non-participants exit

  if (sh_mode == 2)
    scan_loop<XPAD, true >(rank, tid, x0, t_save, W_tau, tau0, W_f, gu, xslot, out, xsp, pre);
  else
    scan_loop<1,    false>(rank, tid, x0, t_save, W_tau, tau0, W_f, gu, xslot, out, xsp, pre);
}

extern "C" void kernel_launch(void* const* d_in, const int* in_sizes, int n_in,
                              void* d_out, int out_size, void* d_ws, size_t ws_size,
                              hipStream_t stream) {
  const float* x0     = (const float*)d_in[0];
  const float* I_seq  = (const float*)d_in[1];
  const float* t_save = (const float*)d_in[2];
  const float* W_tau  = (const float*)d_in[3];
  const float* U_tau  = (const float*)d_in[4];
  const float* b_tau  = (const float*)d_in[5];
  const float* tau0   = (const float*)d_in[6];
  const float* W_f    = (const float*)d_in[7];
  const float* U_f    = (const float*)d_in[8];
  const float* b_f    = (const float*)d_in[9];
  float* out = (float*)d_out;

  char* ws = (char*)d_ws;
  unsigned* ctl   = (unsigned*)ws;                               // [0,2048)
  unsigned* pword = (unsigned*)(ws + 2048);                      // own line
  unsigned long long* xslot = (unsigned long long*)(ws + 4096);  // [2][512][XPAD] u64 = 128KB
  float* gu = (float*)(ws + 4096 + 2 * HID * XPAD * sizeof(unsigned long long) + 4096);

  hipMemsetAsync(ctl, 0, 4096, stream);                          // ctl + pword
  hipMemsetAsync(xslot, 0, 2 * HID * XPAD * sizeof(unsigned long long), stream);
  gu_kernel<<<NEVAL, 256, 0, stream>>>(I_seq, t_save, U_tau, b_tau, U_f, b_f, gu);

  void* args[] = { (void*)&x0, (void*)&t_save, (void*)&W_tau, (void*)&tau0, (void*)&W_f,
                   (void*)&gu, (void*)&xslot, (void*)&ctl, (void*)&pword, (void*)&out };
  hipLaunchCooperativeKernel((const void*)ltc_main, dim3(NLAUNCH), dim3(NTH),
                             args, 0, stream);
}

// Round 8
// 7328.834 us; speedup vs baseline: 1.4345x; 1.4345x over previous
//
#include <hip/hip_runtime.h>
#include <math.h>

#define HID    512
#define NIN    256
#define TIN    4096
#define NSTEP  1023
#define NEVAL  (NSTEP*4)
#define NWG    16
#define SLICE  32          // state elements owned per WG
#define NTH    1024

// searchsorted(linspace(0,1,4096), t, side='left') clipped to [0, 4095]
__device__ __forceinline__ int zoh_index(float t) {
  const float delta = 1.0f / 4095.0f;
  int lo = 0, hi = TIN;
  while (lo < hi) {
    int mid = (lo + hi) >> 1;
    float g = (float)mid * delta;
    if (g < t) lo = mid + 1; else hi = mid;
  }
  return lo > TIN - 1 ? TIN - 1 : lo;
}

// Round-3-proven gu precompute (~0.3-0.5 ms, no spill):
// gu[e][0:512] = U_tau @ I(t_e) + b_tau ; gu[e][512:1024] = U_f @ I(t_e) + b_f
__global__ void __launch_bounds__(256)
gu_kernel(const float* __restrict__ I_seq, const float* __restrict__ t_save,
          const float* __restrict__ U_tau, const float* __restrict__ b_tau,
          const float* __restrict__ U_f,   const float* __restrict__ b_f,
          float* __restrict__ gu)
{
  __shared__ float Ish[NIN];
  const int e = blockIdx.x;
  const int tid = threadIdx.x;
  const int n = e >> 2, s = e & 3;
  const float t0 = t_save[n], t1 = t_save[n + 1];
  const float dt = t1 - t0;
  const float third = 1.0f / 3.0f;
  float t;
  if      (s == 0) t = t0;
  else if (s == 1) t = t0 + dt * third;
  else if (s == 2) t = t0 + (dt * 2.0f) * third;
  else             t = t1;
  const int idx = zoh_index(t);
  Ish[tid] = I_seq[idx * NIN + tid];
  __syncthreads();
  float* go = gu + (size_t)e * 1024;
  #pragma unroll
  for (int m = 0; m < 2; ++m) {
    const float* __restrict__ U = m ? U_f : U_tau;
    const float* __restrict__ b = m ? b_f : b_tau;
    #pragma unroll
    for (int hh = 0; hh < 2; ++hh) {
      const int h = tid + hh * 256;
      const float4* __restrict__ Ur = (const float4*)(U + (size_t)h * NIN);
      float acc = 0.f;
      #pragma unroll 8
      for (int k = 0; k < NIN / 4; ++k) {
        float4 u = Ur[k];
        acc = fmaf(u.x, Ish[4*k+0], acc);
        acc = fmaf(u.y, Ish[4*k+1], acc);
        acc = fmaf(u.z, Ish[4*k+2], acc);
        acc = fmaf(u.w, Ish[4*k+3], acc);
      }
      go[m * 512 + h] = acc + b[h];
    }
  }
}

// Persistent cooperative scan, 16 WGs x 1024 threads.
// Exchange: round-3-proven dense packed (tag<<32 | bits) words, agent-scope
// relaxed atomics at the LLC, parity ping-pong, pure-spin poll.
// CHANGE vs round 3 (the experiment): in-wave tau/f pairing.
//   lane map: seg = tid&15 (16 col-segments of 32), m = (tid>>4)&1 (0=tau,1=f),
//   st = tid>>5 (state within slice). Wave w holds states {2w,2w+1} x {tau,f}.
//   After the 4-level seg reduce, shfl_xor(acc,16) swaps the m-bit: zt,zf land
//   in lane (tid&31)==0 -> elementwise + release store are per-wave. This
//   removes pre[] and the 2nd __syncthreads. xsp is parity double-buffered to
//   replace the dropped barrier's ordering role (reads of xsp[e&1] precede
//   barrier(e+1) in program order; writes for eval e+2 follow it).
__global__ void __launch_bounds__(NTH, 1)
ltc_main(const float* __restrict__ x0, const float* __restrict__ t_save,
         const float* __restrict__ W_tau, const float* __restrict__ tau0,
         const float* __restrict__ W_f,
         const float* __restrict__ gu,
         unsigned long long* xslot,          // [2][512] packed (tag, value)
         float* __restrict__ out)
{
  const int wg   = blockIdx.x;
  const int tid  = threadIdx.x;
  const int seg  = tid & 15;                 // column segment (32 cols)
  const int m    = (tid >> 4) & 1;           // 0 = tau row, 1 = f row
  const int st   = tid >> 5;                 // 0..31 state within slice
  const int base = wg * SLICE;
  const int row  = base + st;

  const float* wrow = ((m == 0)
      ? (W_tau + (size_t)row * HID)
      : (W_f   + (size_t)row * HID)) + seg * 32;

  float4 w4[8];
  #pragma unroll
  for (int t = 0; t < 8; ++t) w4[t] = ((const float4*)wrow)[t];

  __shared__ float xsp[2][16][36];           // stride-36: <=2-way conflicts (free)

  const bool isP = ((tid & 31) == 0);        // producer lane for state `st`

  float y0 = 0.f, k1 = 0.f, k2 = 0.f, k3 = 0.f, curx = 0.f, tz = 0.f;
  if (isP) {
    y0   = x0[row];
    curx = y0;
    tz   = tau0[row];
    out[row] = y0;                           // out[0] = x0
  }

  for (int n = 0; n < NSTEP; ++n) {
    const float t0 = t_save[n], t1 = t_save[n + 1];   // uniform -> SGPR
    const float dt = t1 - t0;
    #pragma unroll
    for (int s = 0; s < 4; ++s) {
      const int e = (n << 2) + s;

      // gu loads issued first: latency hides under the poll below
      float gt = 0.f, gf = 0.f;
      if (isP) {
        const float* g = gu + (size_t)e * 1024 + row;
        gt = g[0];
        gf = g[512];
      }

      // ---- acquire x_e: threads 0..511 spin on packed words, fill LDS ----
      if (tid < HID) {
        float v;
        if (e == 0) {
          v = x0[tid];
        } else {
          const unsigned long long* src = xslot + (size_t)(e & 1) * HID + tid;
          unsigned long long pk;
          do {
            pk = __hip_atomic_load(src, __ATOMIC_RELAXED, __HIP_MEMORY_SCOPE_AGENT);
          } while ((unsigned)(pk >> 32) != (unsigned)e);
          v = __uint_as_float((unsigned)pk);
        }
        xsp[e & 1][tid >> 5][tid & 31] = v;
      }
      __syncthreads();                       // the ONLY barrier per eval

      // ---- matvec: 32 MACs/thread from VGPR weights + LDS x ----
      const float* xs = &xsp[e & 1][seg][0];
      float acc = 0.f;
      #pragma unroll
      for (int t = 0; t < 8; ++t) {
        const float4 xv = ((const float4*)xs)[t];
        acc = fmaf(w4[t].x, xv.x, acc);
        acc = fmaf(w4[t].y, xv.y, acc);
        acc = fmaf(w4[t].z, xv.z, acc);
        acc = fmaf(w4[t].w, xv.w, acc);
      }
      acc += __shfl_xor(acc, 1);
      acc += __shfl_xor(acc, 2);
      acc += __shfl_xor(acc, 4);
      acc += __shfl_xor(acc, 8);
      const float other = __shfl_xor(acc, 16);  // swap tau<->f partner sums

      // ---- elementwise + RK4 update in-wave; packed store IS the release ----
      if (isP) {
        const float zt  = acc + gt;
        const float zf  = other + gf;
        const float ez  = __expf(-fabsf(zt));
        const float sp  = fmaxf(zt, 0.f) + __logf(1.f + ez);
        const float tau = tz + sp;
        const float ef  = __expf(-2.f * fabsf(zf));
        const float th  = (1.f - ef) * __builtin_amdgcn_rcpf(1.f + ef);
        const float f   = (zf >= 0.f) ? th : -th;
        const float d   = f - curx * __builtin_amdgcn_rcpf(tau);
        float xnew;
        if      (s == 0) { k1 = d; xnew = y0 + dt * k1 * (1.0f/3.0f); }
        else if (s == 1) { k2 = d; xnew = y0 + dt * (k2 - k1 * (1.0f/3.0f)); }
        else if (s == 2) { k3 = d; xnew = y0 + dt * (k1 - k2 + k3); }
        else             { xnew = y0 + (k1 + 3.0f * (k2 + k3) + d) * dt * 0.125f; y0 = xnew; }
        curx = xnew;
        const unsigned long long pk =
            ((unsigned long long)(unsigned)(e + 1) << 32) |
            (unsigned long long)__float_as_uint(xnew);
        __hip_atomic_store(xslot + (size_t)((e + 1) & 1) * HID + row, pk,
                           __ATOMIC_RELAXED, __HIP_MEMORY_SCOPE_AGENT);
        if (s == 3) out[(size_t)(n + 1) * HID + row] = xnew;   // after release
      }
    }
  }
}

extern "C" void kernel_launch(void* const* d_in, const int* in_sizes, int n_in,
                              void* d_out, int out_size, void* d_ws, size_t ws_size,
                              hipStream_t stream) {
  const float* x0     = (const float*)d_in[0];
  const float* I_seq  = (const float*)d_in[1];
  const float* t_save = (const float*)d_in[2];
  const float* W_tau  = (const float*)d_in[3];
  const float* U_tau  = (const float*)d_in[4];
  const float* b_tau  = (const float*)d_in[5];
  const float* tau0   = (const float*)d_in[6];
  const float* W_f    = (const float*)d_in[7];
  const float* U_f    = (const float*)d_in[8];
  const float* b_f    = (const float*)d_in[9];
  float* out = (float*)d_out;

  char* ws = (char*)d_ws;
  unsigned long long* xslot = (unsigned long long*)(ws + 1024);  // [2][512] = 8KB
  float* gu = (float*)(ws + 16384);                              // NEVAL*1024 floats (~16.8MB)

  // zero tags every call -> replay-safe, first-call-safe (tag 0 never matches)
  hipMemsetAsync(xslot, 0, 2 * HID * sizeof(unsigned long long), stream);
  gu_kernel<<<NEVAL, 256, 0, stream>>>(I_seq, t_save, U_tau, b_tau, U_f, b_f, gu);

  void* args[] = { (void*)&x0, (void*)&t_save, (void*)&W_tau, (void*)&tau0, (void*)&W_f,
                   (void*)&gu, (void*)&xslot, (void*)&out };
  hipLaunchCooperativeKernel((const void*)ltc_main, dim3(NWG), dim3(NTH),
                             args, 0, stream);
}